// Round 8
// baseline (388.375 us; speedup 1.0000x reference)
//
#include <hip/hip_runtime.h>
#include <math.h>

// ConvKAN3D: 3x [conv3d(3x3x3,pad1) -> cubic KAN spline + SiLU -> BN(eval) -> maxpool 2x2x2]
// then global mean pool + fc1/relu/fc2.
// r18: REGISTER-STAGED PREFETCH (single LDS buffer) for CPG>1 layers.
// r17 quantified L2's limiter: LDS 47.1KB -> 3 blocks/CU -> grid 1024 runs as 2
// ragged rounds (avg 8 waves/CU, measured Occupancy 24.7%). VGPR 76 allows 16
// waves/CU; need LDS <= 40KB for 4 blocks/CU. Fix: prefetch next cin into 6
// float4 VGPRs (two 3-chunk phases A/B to cap peak pressure; A written right
// after the r[] ds_reads, B after the FMA block), ds_write into the SAME
// wave-private buffer -> LDS 47.1 -> 23.7KB -> one clean round @ 16 waves/CU.
// No asm waits: compiler handles vmcnt before ds_write and lgkm on next reads
// (same-array aliasing, wave-private; DS pipe is per-wave in-order).
// Also reverted to measured-good forms: L1 = r12 config (CGO=1, grid 2048, DMA
// stage + vmcnt(0), 33.6us), head split back into mean_kernel + fc_kernel
// (fused single-block head was ~40us vs 15us split -- r13/r16/r17 regressions).
// Kept: scalar s_load weights (readfirstlane, r16/r17: L2 126->121, VGPR 92->76).
// Measured-dead-ends (do not retry): LDS padding/alignment (r15: conflict counter
// structural), TPB=128 (r13), 1 block/CU (r16-L1), fused 1-block head (r17),
// G=8 (r8 spill), cin-split via global atomics (r5). launch_bounds stays (TPB,2).
// CSPLIT scratch indexed by (cg,sw_) jointly (r14 replay race).

#define GLOBAL_AS __attribute__((address_space(1)))
#define LDS_AS    __attribute__((address_space(3)))

static __device__ __forceinline__ void async_ld16(const float* g, float* l) {
    __builtin_amdgcn_global_load_lds((const GLOBAL_AS void*)g, (LDS_AS void*)l,
                                     16, 0, 0);
}

// Pack [C][CIN][27] conv weights -> [C*CIN][28] (16B-aligned float4 x 7, tail 0).
// Tail threads also zero zbuf (no separate memset dispatch).
__global__ __launch_bounds__(256) void repack_kernel(
    const float* __restrict__ w1, const float* __restrict__ w2,
    const float* __restrict__ w3,
    float* __restrict__ o1, float* __restrict__ o2, float* __restrict__ o3,
    float* __restrict__ zbuf)
{
    const int i = blockIdx.x * 256 + threadIdx.x;   // (c,ci) pair id
    const float* src;
    float* dst;
    if (i < 32)            { src = w1 + i * 27;           dst = o1 + i * 28; }
    else if (i < 2080)     { const int j = i - 32;   src = w2 + j * 27; dst = o2 + j * 28; }
    else if (i < 10272)    { const int j = i - 2080; src = w3 + j * 27; dst = o3 + j * 28; }
    else { if (i < 10288) zbuf[i - 10272] = 0.0f; return; }
#pragma unroll
    for (int t = 0; t < 27; t++) dst[t] = src[t];
    dst[27] = 0.0f;
}

template <int TPB_, int CIN, int CSPLIT, int G,
          int WDT, int WHT, int WWT, int BD, int BH, int BW>
__global__ __launch_bounds__(TPB_, 2) void spline_block_kernel(
    const float* __restrict__ x,    // [N, CIN, D, H, W]
    const float4* __restrict__ wpk, // [Cout*CIN][7] packed conv weights
    const float* __restrict__ cb,   // [Cout]
    const float* __restrict__ knots,// [10]
    const float* __restrict__ sw,   // [Cout, 10]
    const float* __restrict__ w1,
    const float* __restrict__ w2,
    const float* __restrict__ g,
    const float* __restrict__ beta,
    const float* __restrict__ zbuf, // >=64B of zeros (16B aligned)
    float* __restrict__ out,        // [N, Cout, D/2, H/2, W/2]
    int N, int Cout, int D, int H, int W,
    int ntiles, int nthw, int ntw)
{
    constexpr int NSW    = BD * BH * BW;       // spatial wave-tiles per block
    constexpr int NW     = TPB_ / 64;          // waves per block
    constexpr int CPG    = CIN / CSPLIT;       // cins per cin-group
    constexpr int ID     = 2 * WDT + 2;        // input planes (d) per wave tile
    constexpr int IH     = 2 * WHT + 2;        // input rows (h) per wave tile
    constexpr int CHK    = (WWT + 4) / 2;      // 16B chunks per input row
    constexpr int PITCH  = CHK * 4;            // dwords per row
    constexpr int ROWS   = ID * IH;
    constexpr int CHUNKS = ROWS * CHK;         // 360 for the 2x4x8 tile
    constexpr int PHYS   = CHUNKS * 4;         // dwords per wave buffer
    constexpr int NCH    = (CHUNKS + 63) / 64; // stage issues per cin per lane
    constexpr int SCRDW  = (CSPLIT > 1) ? (CSPLIT - 1) * NSW * 64 * G * 8 : 0;
    constexpr int TILEDW = (NW * PHYS > SCRDW) ? NW * PHYS : SCRDW;
    static_assert(NW == NSW * CSPLIT, "waves = spatial-tiles x cin-split");
    static_assert(WDT * WHT * WWT == 64, "one wave per spatial tile");
    static_assert(CIN % CSPLIT == 0, "cin divisible");
    static_assert(G == 4, "acc layout assumes G==4");
    static_assert(NCH <= 32, "mask fits u32");
    static_assert(CPG == 1 || NCH == 6, "reg-staged A/B split assumes 6 chunks");

    __shared__ __align__(16) float tile[TILEDW];
    __shared__ float4 stbl[G * 11];            // spline prefix coeffs {A,3B,3C,D}

    const int PD = D >> 1, PH = H >> 1, PW = W >> 1;
    const int groups = Cout / G;
    const int tid  = threadIdx.x;
    const int wv   = tid >> 6;                 // wave id
    const int lane = tid & 63;
    const int sw_  = wv % NSW;                 // spatial wave-tile id
    const int cg   = wv / NSW;                 // cin-group id

    const int bx      = blockIdx.x;
    const int tile_id = bx % ntiles;
    const int t1      = bx / ntiles;
    const int grp     = t1 % groups;
    const int n       = t1 / groups;
    const int c0      = grp * G;
    const int cinbase = cg * CPG;
    // wave-uniform cin base -> uniform weight addresses -> SMEM s_load (lgkmcnt,
    // separate counter from VMEM, zero VGPR cost)
    const int cinbase_u = __builtin_amdgcn_readfirstlane(cinbase);

    const int td  = tile_id / nthw;
    const int rem = tile_id % nthw;
    const int th_ = rem / ntw;
    const int tw_ = rem % ntw;

    // spline prefix-coeff table (covered by the single initial barrier)
    for (int i = tid; i < G * 11; i += TPB_) {
        const int gg  = i / 11;
        const int cnt = i % 11;
        const int c   = c0 + gg;
        float A = 0.f, B3 = 0.f, C3 = 0.f, Dd = 0.f;
        for (int j = 0; j < cnt; j++) {
            const float s = sw[c * 10 + j];
            const float k = knots[j];
            A  += s;
            B3 += 3.0f * s * k;
            C3 += 3.0f * s * k * k;
            Dd += s * k * k * k;
        }
        stbl[i] = make_float4(A, B3, C3, Dd);
    }

    // wave spatial origin (pooled coords)
    const int swd = sw_ / (BH * BW);
    const int r2  = sw_ % (BH * BW);
    const int swh = r2 / BW;
    const int sww = r2 % BW;
    const int pd0 = td  * (BD * WDT) + swd * WDT;
    const int ph0 = th_ * (BH * WHT) + swh * WHT;
    const int pw0 = tw_ * (BW * WWT) + sww * WWT;

    const int pwl = lane % WWT;
    const int phl = (lane / WWT) % WHT;
    const int pdl = lane / (WWT * WHT);

    const int d0 = 2 * pd0 - 1, h0 = 2 * ph0 - 1;
    const int w0 = 2 * pw0 - 1;
    const int wb = w0 & ~3;                    // 4-dword aligned chunk origin
    const int woff = w0 - wb;                  // 1 or 3

    // per-chunk global offsets + validity (per wave tile, same for all cins)
    int off[NCH];
    unsigned vm = 0;
#pragma unroll
    for (int k = 0; k < NCH; k++) {
        const int chunk = lane + 64 * k;
        const int row = chunk / CHK, cs = chunk - row * CHK;
        const int dz = row / IH, hy = row - dz * IH;
        const int dd = d0 + dz, hh = h0 + hy;
        const int wsd = wb + cs * 4;
        const bool ok = (chunk < CHUNKS) &
                        ((unsigned)dd < (unsigned)D) &
                        ((unsigned)hh < (unsigned)H) &
                        ((unsigned)wsd < (unsigned)W);
        off[k] = ok ? (dd * H + hh) * W + wsd : 0;
        vm |= (unsigned)ok << k;
    }

    const size_t chstride = (size_t)D * H * W;
    const float* xn = x + (size_t)n * CIN * chstride;
    float* myt = tile + wv * PHYS;             // wave-private staging buffer

    float acc[G][8];
#pragma unroll
    for (int gg = 0; gg < G; gg++)
#pragma unroll
        for (int i = 0; i < 8; i++) acc[gg][i] = 0.0f;

    __syncthreads();   // stbl visible; clean slate

    // ---- staging helpers -------------------------------------------------
    // DMA path (CPG==1 only): global_load_lds w16
    auto stage_dma = [&](int ci) {
        const float* xc = xn + (size_t)ci * chstride;
#pragma unroll
        for (int k = 0; k < NCH; k++) {
            const int chunk = lane + 64 * k;
            if ((k + 1) * 64 <= CHUNKS || chunk < CHUNKS) {
                const float* src = ((vm >> k) & 1) ? (xc + off[k]) : zbuf;
                async_ld16(src, myt + chunk * 4);
            }
        }
    };
    // reg path (CPG>1): two 3-chunk phases into VGPRs, ds_write into same buffer
    float4 nxa[3], nxb[3];
    auto ld_a = [&](int ci) {
        const float* xc = xn + (size_t)ci * chstride;
#pragma unroll
        for (int k = 0; k < 3; k++) {
            const float* src = ((vm >> k) & 1) ? (xc + off[k]) : zbuf;
            nxa[k] = *reinterpret_cast<const float4*>(src);
        }
    };
    auto ld_b = [&](int ci) {
        const float* xc = xn + (size_t)ci * chstride;
#pragma unroll
        for (int k = 3; k < NCH; k++) {
            const float* src = ((vm >> k) & 1) ? (xc + off[k]) : zbuf;
            nxb[k - 3] = *reinterpret_cast<const float4*>(src);
        }
    };
    auto wr_a = [&]() {
#pragma unroll
        for (int k = 0; k < 3; k++)
            *reinterpret_cast<float4*>(myt + (lane + 64 * k) * 4) = nxa[k];
    };
    auto wr_b = [&]() {
#pragma unroll
        for (int k = 3; k < NCH; k++) {
            const int chunk = lane + 64 * k;
            if ((k + 1) * 64 <= CHUNKS || chunk < CHUNKS)
                *reinterpret_cast<float4*>(myt + chunk * 4) = nxb[k - 3];
        }
    };
    // ----------------------------------------------------------------------

    // prologue: stage first cin
    if constexpr (CPG == 1) {
        stage_dma(cinbase);
        asm volatile("s_waitcnt vmcnt(0)" ::: "memory");
    } else {
        ld_a(cinbase); wr_a();
        ld_b(cinbase); wr_b();
    }

#pragma unroll 1
    for (int s = 0; s < CPG; s++) {
        if constexpr (CPG > 1) {
            if (s + 1 < CPG) ld_a(cinbase + s + 1);   // phase-A prefetch in flight
        }

        const int ci_u = cinbase_u + s;        // wave-uniform weight row
        float r[64];
#pragma unroll
        for (int dz = 0; dz < 4; dz++)
#pragma unroll
        for (int dy = 0; dy < 4; dy++) {
            const int rb = ((2 * pdl + dz) * IH + (2 * phl + dy)) * PITCH +
                           woff + 2 * pwl;
            r[(dz * 4 + dy) * 4 + 0] = myt[rb + 0];
            r[(dz * 4 + dy) * 4 + 1] = myt[rb + 1];
            r[(dz * 4 + dy) * 4 + 2] = myt[rb + 2];
            r[(dz * 4 + dy) * 4 + 3] = myt[rb + 3];
        }

        if constexpr (CPG > 1) {
            if (s + 1 < CPG) {
                wr_a();                        // reads of current tile are done
                ld_b(cinbase + s + 1);         // phase-B in flight over FMA
            }
        }

#pragma unroll
        for (int gg = 0; gg < G; gg++) {
            // uniform address -> s_load (SMEM), separate lgkm counter
            const float4* wq = wpk + ((size_t)(c0 + gg) * CIN + ci_u) * 7;
            float4 q[7];
#pragma unroll
            for (int ch = 0; ch < 7; ch++) q[ch] = wq[ch];
#pragma unroll
            for (int ch = 0; ch < 7; ch++) {
#pragma unroll
                for (int j = 0; j < 4; j++) {
                    const int tap = ch * 4 + j;
                    if (tap < 27) {
                        const float wvj = (j == 0) ? q[ch].x : (j == 1) ? q[ch].y
                                        : (j == 2) ? q[ch].z : q[ch].w;
                        const int kd = tap / 9, kh = (tap % 9) / 3, kw = tap % 3;
#pragma unroll
                        for (int od = 0; od < 2; od++)
#pragma unroll
                        for (int oh = 0; oh < 2; oh++)
#pragma unroll
                        for (int ow = 0; ow < 2; ow++)
                            acc[gg][(od * 2 + oh) * 2 + ow] =
                                fmaf(wvj,
                                     r[((od + kd) * 4 + (oh + kh)) * 4 + (ow + kw)],
                                     acc[gg][(od * 2 + oh) * 2 + ow]);
                    }
                }
            }
        }

        if constexpr (CPG > 1) {
            if (s + 1 < CPG) wr_b();           // buffer complete for next step
        }
    }

    // combine partial accumulators across cin-groups (scratch aliases tile).
    // scratch MUST be indexed by (cg, sw_) jointly (r14 replay race).
    float* af = &acc[0][0];
    if (CSPLIT > 1) {
        __syncthreads();                        // all waves done with their tiles
        float* scratch = tile;
        if (cg > 0) {
#pragma unroll
            for (int idx = 0; idx < G * 8; idx++)
                scratch[((idx * (CSPLIT - 1) + (cg - 1)) * NSW + sw_) * 64 + lane]
                    = af[idx];
        }
        __syncthreads();
        if (cg == 0) {
#pragma unroll
            for (int idx = 0; idx < G * 8; idx++) {
                float s2 = af[idx];
                for (int j = 0; j < CSPLIT - 1; j++)
                    s2 += scratch[((idx * (CSPLIT - 1) + j) * NSW + sw_) * 64 + lane];
                af[idx] = s2;
            }
        }
    }

    // epilogue (cin-group 0): bias + spline (prefix-Horner) + SiLU + BN + maxpool
    if (cg == 0) {
        const int pdg = pd0 + pdl, phg = ph0 + phl, pwg = pw0 + pwl;
#pragma unroll
        for (int gg = 0; gg < G; gg++) {
            const int c = c0 + gg;
            const float bias = cb[c];
            const float W1 = w1[c], W2 = w2[c];
            const float scale = g[c] * rsqrtf(1.0f + 1e-5f);
            const float bb = beta[c];
            float m = -INFINITY;
#pragma unroll
            for (int i = 0; i < 8; i++) {
                const float y = acc[gg][i] + bias;
                int idx = (int)floorf((y + 1.0f) * 4.5f) + 1;
                idx = min(max(idx, 0), 10);
                const float4 cf = stbl[gg * 11 + idx];
                const float sp = ((cf.x * y - cf.y) * y + cf.z) * y - cf.w;
                const float silu = y / (1.0f + __expf(-y));
                const float o = fmaf(W1 * sp + W2 * silu, scale, bb);
                m = fmaxf(m, o);
            }
            out[((size_t)(n * Cout + c) * PD + pdg) * PH * PW + phg * PW + pwg] = m;
        }
    }
}

// Global average pool: one wave per (n,c)  (r12-measured ~3us)
__global__ __launch_bounds__(64) void mean_kernel(
    const float* __restrict__ h, float* __restrict__ out, int S)
{
    const int nc = blockIdx.x;
    const int lane = threadIdx.x;
    const float* p = h + (size_t)nc * S;
    float s = 0.0f;
    for (int i = lane; i < S; i += 64) s += p[i];
#pragma unroll
    for (int off = 32; off > 0; off >>= 1) s += __shfl_down(s, off, 64);
    if (lane == 0) out[nc] = s / (float)S;
}

// fc1(128->256)+ReLU then fc2(256->2), batch 2  (r12-measured ~12us)
__global__ __launch_bounds__(256) void fc_kernel(
    const float* __restrict__ pooled,
    const float* __restrict__ w1, const float* __restrict__ b1,
    const float* __restrict__ w2, const float* __restrict__ b2,
    float* __restrict__ out)
{
    __shared__ float hbuf[2][256];
    const int j = threadIdx.x;
#pragma unroll
    for (int nn = 0; nn < 2; nn++) {
        float s = b1[j];
        for (int k = 0; k < 128; k++)
            s = fmaf(pooled[nn * 128 + k], w1[j * 128 + k], s);
        hbuf[nn][j] = fmaxf(s, 0.0f);
    }
    __syncthreads();
    const int wid = j >> 6, lane = j & 63;
    const int nn = wid >> 1, oo = wid & 1;
    float s = 0.0f;
    for (int k = lane; k < 256; k += 64) s += hbuf[nn][k] * w2[oo * 256 + k];
#pragma unroll
    for (int off = 32; off > 0; off >>= 1) s += __shfl_down(s, off, 64);
    if (lane == 0) out[nn * 2 + oo] = s + b2[oo];
}

extern "C" void kernel_launch(void* const* d_in, const int* in_sizes, int n_in,
                              void* d_out, int out_size, void* d_ws, size_t ws_size,
                              hipStream_t stream) {
    const float* x      = (const float*)d_in[0];
    const float* c1_w   = (const float*)d_in[1];
    const float* c1_b   = (const float*)d_in[2];
    const float* c1_kn  = (const float*)d_in[3];
    const float* c1_sw  = (const float*)d_in[4];
    const float* c1_w1  = (const float*)d_in[5];
    const float* c1_w2  = (const float*)d_in[6];
    const float* bn1_g  = (const float*)d_in[7];
    const float* bn1_b  = (const float*)d_in[8];
    const float* c2_w   = (const float*)d_in[9];
    const float* c2_b   = (const float*)d_in[10];
    const float* c2_kn  = (const float*)d_in[11];
    const float* c2_sw  = (const float*)d_in[12];
    const float* c2_w1  = (const float*)d_in[13];
    const float* c2_w2  = (const float*)d_in[14];
    const float* bn2_g  = (const float*)d_in[15];
    const float* bn2_b  = (const float*)d_in[16];
    const float* c3_w   = (const float*)d_in[17];
    const float* c3_b   = (const float*)d_in[18];
    const float* c3_kn  = (const float*)d_in[19];
    const float* c3_sw  = (const float*)d_in[20];
    const float* c3_w1  = (const float*)d_in[21];
    const float* c3_w2  = (const float*)d_in[22];
    const float* bn3_g  = (const float*)d_in[23];
    const float* bn3_b  = (const float*)d_in[24];
    const float* fc1_w  = (const float*)d_in[25];
    const float* fc1_b  = (const float*)d_in[26];
    const float* fc2_w  = (const float*)d_in[27];
    const float* fc2_b  = (const float*)d_in[28];

    float* ws = (float*)d_ws;
    float* h1     = ws;                  // 2*32*32^3 = 2,097,152 fl
    float* h2     = h1 + 2097152;        // 2*64*16^3 =   524,288 fl
    float* h3     = h2 + 524288;         // 2*128*8^3 =   131,072 fl
    float* pooled = h3 + 131072;         // 256 fl
    float* zbuf   = pooled + 256;        // 64 B zeros (16B aligned)
    float* wp1    = zbuf + 16;           // 32*1*28   =       896 fl (16B aligned)
    float* wp2    = wp1 + 896;           // 64*32*28  =    57,344 fl
    float* wp3    = wp2 + 57344;         // 128*64*28 =   229,376 fl

    // pack all conv weights to pitch-28 (aligned float4 x7) + zero zbuf
    repack_kernel<<<dim3(41), dim3(256), 0, stream>>>(c1_w, c2_w, c3_w,
                                                      wp1, wp2, wp3, zbuf);

    // All layers: wave tile 2x4x8 (ID=6, IH=10, PITCH=24).
    // L1: (2,1,64^3)->(2,32,32^3). r12 config: 4 spatial waves (2x2x1), DMA
    // stage + vmcnt(0). LDS 23.7KB -> 4 blocks/CU; grid 2048 = 2 clean rounds.
    spline_block_kernel<256, 1, 1, 4, 2, 4, 8, 2, 2, 1>
        <<<dim3(2048), dim3(256), 0, stream>>>(
        x, (const float4*)wp1, c1_b, c1_kn, c1_sw, c1_w1, c1_w2, bn1_g, bn1_b,
        zbuf, h1, 2, 32, 64, 64, 64, 128, 16, 4);
    // L2: (2,32,32^3)->(2,64,16^3). CSPLIT=2 x 2 spatial waves, reg-staged
    // single buffer: LDS 23.7KB -> 4 blocks/CU = 16 waves/CU; grid 1024 =
    // ONE clean round (was 2 ragged rounds at avg 8 waves/CU).
    spline_block_kernel<256, 32, 2, 4, 2, 4, 8, 1, 1, 2>
        <<<dim3(1024), dim3(256), 0, stream>>>(
        h1, (const float4*)wp2, c2_b, c2_kn, c2_sw, c2_w1, c2_w2, bn2_g, bn2_b,
        zbuf, h2, 2, 64, 32, 32, 32, 32, 4, 1);
    // L3: (2,64,16^3)->(2,128,8^3). CSPLIT=4, reg-staged. LDS 25.3KB.
    // grid = 2*32*8 = 512 (grid-limited).
    spline_block_kernel<256, 64, 4, 4, 2, 4, 8, 1, 1, 1>
        <<<dim3(512), dim3(256), 0, stream>>>(
        h2, (const float4*)wp3, c3_b, c3_kn, c3_sw, c3_w1, c3_w2, bn3_g, bn3_b,
        zbuf, h3, 2, 128, 16, 16, 16, 8, 2, 1);
    // head: split kernels (measured 3us + 12us; fused 1-block head was ~40us)
    mean_kernel<<<dim3(256), dim3(64), 0, stream>>>(h3, pooled, 512);
    fc_kernel<<<dim3(1), dim3(256), 0, stream>>>(pooled, fc1_w, fc1_b, fc2_w, fc2_b,
                                                 (float*)d_out);
}

// Round 9
// 320.590 us; speedup vs baseline: 1.2114x; 1.2114x over previous
//
#include <hip/hip_runtime.h>
#include <math.h>

// ConvKAN3D: 3x [conv3d(3x3x3,pad1) -> cubic KAN spline + SiLU -> BN(eval) -> maxpool 2x2x2]
// then global mean pool + fc1/relu/fc2.
// r19: BEST-OF ASSEMBLY + MEAN FUSED INTO L3.
//  - K-loop: r17's exact measured form (dbuf DMA global_load_lds w16, counted
//    s_waitcnt vmcnt(6), scalar s_load weights via readfirstlane).
//  - L1 = r12 config (grid 2048, CPG=1): measured 33.6us.
//  - L2 = r17 config (CSPLIT=2 x NSW=2, dbuf): measured 121.3us.
//  - L3 = r17 config (CSPLIT=4) + FUSED MEAN: epilogue wave-reduces the maxpool
//    outputs and atomicAdds scaled partials into pooled[] (device-scope; written
//    only here, read by fc_kernel AFTER a kernel boundary -> no cross-XCD read
//    hazard). h3 never materialized; mean_kernel dispatch + gap eliminated.
//  - pooled/zbuf zeroed inside repack_kernel every launch (graph-replay safe).
//  - 5 dispatches (repack, L1, L2, L3, fc); r12-r17 showed ~70-90us of
//    inter-dispatch gaps at 6-7 dispatches.
// Measured-dead-ends (do not retry): reg-staged prefetch w/ r[64] (r18: scratch
// spill, WRITE 168MB, L2 174us), LDS padding/alignment (r15: conflict counter is
// structural 1.049e7 regardless; dur worse), TPB=128 (r13), 1 block/CU (r16-L1),
// fused 1-block head (r17), G=8 (r8 spill), cin-split via global atomics on the
// conv accumulators (r5). launch_bounds stays (TPB,2). CSPLIT scratch indexed by
// (cg,sw_) jointly (r14 replay race).

#define GLOBAL_AS __attribute__((address_space(1)))
#define LDS_AS    __attribute__((address_space(3)))

static __device__ __forceinline__ void async_ld16(const float* g, float* l) {
    __builtin_amdgcn_global_load_lds((const GLOBAL_AS void*)g, (LDS_AS void*)l,
                                     16, 0, 0);
}

// Pack [C][CIN][27] conv weights -> [C*CIN][28] (16B-aligned float4 x 7, tail 0).
// Tail threads zero zbuf and pooled (replay-safe accumulator reset, no extra
// dispatch).
__global__ __launch_bounds__(256) void repack_kernel(
    const float* __restrict__ w1, const float* __restrict__ w2,
    const float* __restrict__ w3,
    float* __restrict__ o1, float* __restrict__ o2, float* __restrict__ o3,
    float* __restrict__ zbuf, float* __restrict__ pooled)
{
    const int i = blockIdx.x * 256 + threadIdx.x;   // (c,ci) pair id
    const float* src;
    float* dst;
    if (i < 32)            { src = w1 + i * 27;           dst = o1 + i * 28; }
    else if (i < 2080)     { const int j = i - 32;   src = w2 + j * 27; dst = o2 + j * 28; }
    else if (i < 10272)    { const int j = i - 2080; src = w3 + j * 27; dst = o3 + j * 28; }
    else {
        if (i < 10288) zbuf[i - 10272] = 0.0f;
        else if (i < 10544) pooled[i - 10288] = 0.0f;
        return;
    }
#pragma unroll
    for (int t = 0; t < 27; t++) dst[t] = src[t];
    dst[27] = 0.0f;
}

template <int TPB_, int CIN, int CSPLIT, int G,
          int WDT, int WHT, int WWT, int BD, int BH, int BW, bool FMEAN>
__global__ __launch_bounds__(TPB_, 2) void spline_block_kernel(
    const float* __restrict__ x,    // [N, CIN, D, H, W]
    const float4* __restrict__ wpk, // [Cout*CIN][7] packed conv weights
    const float* __restrict__ cb,   // [Cout]
    const float* __restrict__ knots,// [10]
    const float* __restrict__ sw,   // [Cout, 10]
    const float* __restrict__ w1,
    const float* __restrict__ w2,
    const float* __restrict__ g,
    const float* __restrict__ beta,
    const float* __restrict__ zbuf, // >=64B of zeros (16B aligned)
    float* __restrict__ out,        // FMEAN? pooled[N*Cout] : [N,Cout,D/2,H/2,W/2]
    int N, int Cout, int D, int H, int W,
    int ntiles, int nthw, int ntw)
{
    constexpr int NSW    = BD * BH * BW;       // spatial wave-tiles per block
    constexpr int NW     = TPB_ / 64;          // waves per block
    constexpr int CPG    = CIN / CSPLIT;       // cins per cin-group
    constexpr int ID     = 2 * WDT + 2;        // input planes (d) per wave tile
    constexpr int IH     = 2 * WHT + 2;        // input rows (h) per wave tile
    constexpr int CHK    = (WWT + 4) / 2;      // 16B chunks per input row
    constexpr int PITCH  = CHK * 4;            // dwords per row
    constexpr int ROWS   = ID * IH;
    constexpr int CHUNKS = ROWS * CHK;
    constexpr int PHYS   = CHUNKS * 4;         // dwords per wave buffer
    constexpr int NCH    = (CHUNKS + 63) / 64; // DMA issues per cin per lane
    constexpr int BUFS   = (CPG > 1) ? 2 : 1;
    static_assert(NW == NSW * CSPLIT, "waves = spatial-tiles x cin-split");
    static_assert(WDT * WHT * WWT == 64, "one wave per spatial tile");
    static_assert(CIN % CSPLIT == 0, "cin divisible");
    static_assert(G == 4, "acc layout assumes G==4");
    static_assert(NCH <= 32, "mask fits u32");
    static_assert(NCH == 6, "s_waitcnt vmcnt(6) literal assumes 6 issues/cin");
    static_assert(CSPLIT == 1 ||
                  (CSPLIT - 1) * NSW * 64 * G * 8 <= NW * BUFS * PHYS,
                  "reduction scratch fits in tile");

    __shared__ __align__(16) float tile[NW][BUFS][PHYS];
    __shared__ float4 stbl[G * 11];            // spline prefix coeffs {A,3B,3C,D}

    const int PD = D >> 1, PH = H >> 1, PW = W >> 1;
    const int groups = Cout / G;
    const int tid  = threadIdx.x;
    const int wv   = tid >> 6;                 // wave id
    const int lane = tid & 63;
    const int sw_  = wv % NSW;                 // spatial wave-tile id
    const int cg   = wv / NSW;                 // cin-group id

    const int bx      = blockIdx.x;
    const int tile_id = bx % ntiles;
    const int t1      = bx / ntiles;
    const int grp     = t1 % groups;
    const int n       = t1 / groups;
    const int c0      = grp * G;
    const int cinbase = cg * CPG;
    // wave-uniform cin base -> uniform weight addresses -> SMEM s_load (lgkmcnt,
    // separate counter from the staging DMAs' vmcnt, zero VGPR cost)
    const int cinbase_u = __builtin_amdgcn_readfirstlane(cinbase);

    const int td  = tile_id / nthw;
    const int rem = tile_id % nthw;
    const int th_ = rem / ntw;
    const int tw_ = rem % ntw;

    // spline prefix-coeff table (covered by the single initial barrier)
    for (int i = tid; i < G * 11; i += TPB_) {
        const int gg  = i / 11;
        const int cnt = i % 11;
        const int c   = c0 + gg;
        float A = 0.f, B3 = 0.f, C3 = 0.f, Dd = 0.f;
        for (int j = 0; j < cnt; j++) {
            const float s = sw[c * 10 + j];
            const float k = knots[j];
            A  += s;
            B3 += 3.0f * s * k;
            C3 += 3.0f * s * k * k;
            Dd += s * k * k * k;
        }
        stbl[i] = make_float4(A, B3, C3, Dd);
    }

    // wave spatial origin (pooled coords)
    const int swd = sw_ / (BH * BW);
    const int r2  = sw_ % (BH * BW);
    const int swh = r2 / BW;
    const int sww = r2 % BW;
    const int pd0 = td  * (BD * WDT) + swd * WDT;
    const int ph0 = th_ * (BH * WHT) + swh * WHT;
    const int pw0 = tw_ * (BW * WWT) + sww * WWT;

    const int pwl = lane % WWT;
    const int phl = (lane / WWT) % WHT;
    const int pdl = lane / (WWT * WHT);

    const int d0 = 2 * pd0 - 1, h0 = 2 * ph0 - 1;
    const int w0 = 2 * pw0 - 1;
    const int wb = w0 & ~3;                    // 4-dword aligned chunk origin
    const int woff = w0 - wb;                  // 1 or 3

    // per-chunk global offsets + validity (per wave tile, same for all cins)
    int off[NCH];
    unsigned vm = 0;
#pragma unroll
    for (int k = 0; k < NCH; k++) {
        const int chunk = lane + 64 * k;
        const int row = chunk / CHK, cs = chunk - row * CHK;
        const int dz = row / IH, hy = row - dz * IH;
        const int dd = d0 + dz, hh = h0 + hy;
        const int wsd = wb + cs * 4;
        const bool ok = (chunk < CHUNKS) &
                        ((unsigned)dd < (unsigned)D) &
                        ((unsigned)hh < (unsigned)H) &
                        ((unsigned)wsd < (unsigned)W);
        off[k] = ok ? (dd * H + hh) * W + wsd : 0;
        vm |= (unsigned)ok << k;
    }

    const size_t chstride = (size_t)D * H * W;
    const float* xn = x + (size_t)n * CIN * chstride;

    float acc[G][8];
#pragma unroll
    for (int gg = 0; gg < G; gg++)
#pragma unroll
        for (int i = 0; i < 8; i++) acc[gg][i] = 0.0f;

    __syncthreads();   // stbl visible; vmcnt drained (clean slate)

    auto stage = [&](int ci, int buf) {
        const float* xc = xn + (size_t)ci * chstride;
        float* dst = &tile[wv][buf][0];
#pragma unroll
        for (int k = 0; k < NCH; k++) {
            const int chunk = lane + 64 * k;
            if ((k + 1) * 64 <= CHUNKS || chunk < CHUNKS) {
                const float* src = ((vm >> k) & 1) ? (xc + off[k]) : zbuf;
                async_ld16(src, dst + chunk * 4);
            }
        }
    };

    // prologue: each wave stages its first cin into its buf 0
    stage(cinbase, 0);

#pragma unroll 1
    for (int s = 0; s < CPG; s++) {
        const int cur = s & (BUFS - 1);
        if (s + 1 < CPG) {
            stage(cinbase + s + 1, cur ^ 1);   // 6 DMA issues, stay in flight
            asm volatile("s_waitcnt vmcnt(6)" ::: "memory");  // cin s landed
        } else {
            asm volatile("s_waitcnt vmcnt(0)" ::: "memory");
        }

        const int ci_u = cinbase_u + s;        // wave-uniform weight row
        const float* tb = &tile[wv][cur][0];
        float r[64];
#pragma unroll
        for (int dz = 0; dz < 4; dz++)
#pragma unroll
        for (int dy = 0; dy < 4; dy++) {
            const int rb = ((2 * pdl + dz) * IH + (2 * phl + dy)) * PITCH +
                           woff + 2 * pwl;
            r[(dz * 4 + dy) * 4 + 0] = tb[rb + 0];
            r[(dz * 4 + dy) * 4 + 1] = tb[rb + 1];
            r[(dz * 4 + dy) * 4 + 2] = tb[rb + 2];
            r[(dz * 4 + dy) * 4 + 3] = tb[rb + 3];
        }

#pragma unroll
        for (int gg = 0; gg < G; gg++) {
            // uniform address -> s_load (SMEM), separate lgkm counter
            const float4* wq = wpk + ((size_t)(c0 + gg) * CIN + ci_u) * 7;
            float4 q[7];
#pragma unroll
            for (int ch = 0; ch < 7; ch++) q[ch] = wq[ch];
#pragma unroll
            for (int ch = 0; ch < 7; ch++) {
#pragma unroll
                for (int j = 0; j < 4; j++) {
                    const int tap = ch * 4 + j;
                    if (tap < 27) {
                        const float wvj = (j == 0) ? q[ch].x : (j == 1) ? q[ch].y
                                        : (j == 2) ? q[ch].z : q[ch].w;
                        const int kd = tap / 9, kh = (tap % 9) / 3, kw = tap % 3;
#pragma unroll
                        for (int od = 0; od < 2; od++)
#pragma unroll
                        for (int oh = 0; oh < 2; oh++)
#pragma unroll
                        for (int ow = 0; ow < 2; ow++)
                            acc[gg][(od * 2 + oh) * 2 + ow] =
                                fmaf(wvj,
                                     r[((od + kd) * 4 + (oh + kh)) * 4 + (ow + kw)],
                                     acc[gg][(od * 2 + oh) * 2 + ow]);
                    }
                }
            }
        }
    }

    // combine partial accumulators across cin-groups (scratch aliases tile).
    // scratch MUST be indexed by (cg, sw_) jointly (r14 replay race).
    float* af = &acc[0][0];
    if (CSPLIT > 1) {
        __syncthreads();                        // all waves done with their tiles
        float* scratch = &tile[0][0][0];
        if (cg > 0) {
#pragma unroll
            for (int idx = 0; idx < G * 8; idx++)
                scratch[((idx * (CSPLIT - 1) + (cg - 1)) * NSW + sw_) * 64 + lane]
                    = af[idx];
        }
        __syncthreads();
        if (cg == 0) {
#pragma unroll
            for (int idx = 0; idx < G * 8; idx++) {
                float s2 = af[idx];
                for (int j = 0; j < CSPLIT - 1; j++)
                    s2 += scratch[((idx * (CSPLIT - 1) + j) * NSW + sw_) * 64 + lane];
                af[idx] = s2;
            }
        }
    }

    // epilogue (cin-group 0): bias + spline (prefix-Horner) + SiLU + BN + maxpool
    if (cg == 0) {
        const int pdg = pd0 + pdl, phg = ph0 + phl, pwg = pw0 + pwl;
        const float inv_vol = 1.0f / (float)(PD * PH * PW);
#pragma unroll
        for (int gg = 0; gg < G; gg++) {
            const int c = c0 + gg;
            const float bias = cb[c];
            const float W1 = w1[c], W2 = w2[c];
            const float scale = g[c] * rsqrtf(1.0f + 1e-5f);
            const float bb = beta[c];
            float m = -INFINITY;
#pragma unroll
            for (int i = 0; i < 8; i++) {
                const float y = acc[gg][i] + bias;
                int idx = (int)floorf((y + 1.0f) * 4.5f) + 1;
                idx = min(max(idx, 0), 10);
                const float4 cf = stbl[gg * 11 + idx];
                const float sp = ((cf.x * y - cf.y) * y + cf.z) * y - cf.w;
                const float silu = y / (1.0f + __expf(-y));
                const float o = fmaf(W1 * sp + W2 * silu, scale, bb);
                m = fmaxf(m, o);
            }
            if constexpr (FMEAN) {
                // fused global-mean: wave-reduce this tile's 64 pooled outputs,
                // one device-scope atomicAdd per (block, cout). pooled is
                // write-only here; fc_kernel reads it after the kernel boundary.
                float ssum = m;
#pragma unroll
                for (int o2 = 32; o2 > 0; o2 >>= 1)
                    ssum += __shfl_down(ssum, o2, 64);
                if (lane == 0)
                    atomicAdd(&out[(size_t)n * Cout + c], ssum * inv_vol);
            } else {
                out[((size_t)(n * Cout + c) * PD + pdg) * PH * PW +
                    phg * PW + pwg] = m;
            }
        }
    }
}

// fc1(128->256)+ReLU then fc2(256->2), batch 2. pooled already holds means.
__global__ __launch_bounds__(256) void fc_kernel(
    const float* __restrict__ pooled,
    const float* __restrict__ w1, const float* __restrict__ b1,
    const float* __restrict__ w2, const float* __restrict__ b2,
    float* __restrict__ out)
{
    __shared__ float hbuf[2][256];
    const int j = threadIdx.x;
#pragma unroll
    for (int nn = 0; nn < 2; nn++) {
        float s = b1[j];
        for (int k = 0; k < 128; k++)
            s = fmaf(pooled[nn * 128 + k], w1[j * 128 + k], s);
        hbuf[nn][j] = fmaxf(s, 0.0f);
    }
    __syncthreads();
    const int wid = j >> 6, lane = j & 63;
    const int nn = wid >> 1, oo = wid & 1;
    float s = 0.0f;
    for (int k = lane; k < 256; k += 64) s += hbuf[nn][k] * w2[oo * 256 + k];
#pragma unroll
    for (int off = 32; off > 0; off >>= 1) s += __shfl_down(s, off, 64);
    if (lane == 0) out[nn * 2 + oo] = s + b2[oo];
}

extern "C" void kernel_launch(void* const* d_in, const int* in_sizes, int n_in,
                              void* d_out, int out_size, void* d_ws, size_t ws_size,
                              hipStream_t stream) {
    const float* x      = (const float*)d_in[0];
    const float* c1_w   = (const float*)d_in[1];
    const float* c1_b   = (const float*)d_in[2];
    const float* c1_kn  = (const float*)d_in[3];
    const float* c1_sw  = (const float*)d_in[4];
    const float* c1_w1  = (const float*)d_in[5];
    const float* c1_w2  = (const float*)d_in[6];
    const float* bn1_g  = (const float*)d_in[7];
    const float* bn1_b  = (const float*)d_in[8];
    const float* c2_w   = (const float*)d_in[9];
    const float* c2_b   = (const float*)d_in[10];
    const float* c2_kn  = (const float*)d_in[11];
    const float* c2_sw  = (const float*)d_in[12];
    const float* c2_w1  = (const float*)d_in[13];
    const float* c2_w2  = (const float*)d_in[14];
    const float* bn2_g  = (const float*)d_in[15];
    const float* bn2_b  = (const float*)d_in[16];
    const float* c3_w   = (const float*)d_in[17];
    const float* c3_b   = (const float*)d_in[18];
    const float* c3_kn  = (const float*)d_in[19];
    const float* c3_sw  = (const float*)d_in[20];
    const float* c3_w1  = (const float*)d_in[21];
    const float* c3_w2  = (const float*)d_in[22];
    const float* bn3_g  = (const float*)d_in[23];
    const float* bn3_b  = (const float*)d_in[24];
    const float* fc1_w  = (const float*)d_in[25];
    const float* fc1_b  = (const float*)d_in[26];
    const float* fc2_w  = (const float*)d_in[27];
    const float* fc2_b  = (const float*)d_in[28];

    float* ws = (float*)d_ws;
    float* h1     = ws;                  // 2*32*32^3 = 2,097,152 fl
    float* h2     = h1 + 2097152;        // 2*64*16^3 =   524,288 fl
    float* pooled = h2 + 524288;         // 256 fl (atomic accumulator)
    float* zbuf   = pooled + 256;        // 64 B zeros (16B aligned)
    float* wp1    = zbuf + 16;           // 32*1*28   =       896 fl (16B aligned)
    float* wp2    = wp1 + 896;           // 64*32*28  =    57,344 fl
    float* wp3    = wp2 + 57344;         // 128*64*28 =   229,376 fl

    // pack conv weights (pitch-28 float4x7) + zero zbuf & pooled (replay-safe)
    repack_kernel<<<dim3(42), dim3(256), 0, stream>>>(c1_w, c2_w, c3_w,
                                                      wp1, wp2, wp3, zbuf, pooled);

    // All layers: wave tile 2x4x8 (ID=6, IH=10, PITCH=24, 6 DMA issues/cin).
    // L1: (2,1,64^3)->(2,32,32^3). r12 config (measured 33.6us): 4 spatial
    // waves (2x2x1), grid 2048.
    spline_block_kernel<256, 1, 1, 4, 2, 4, 8, 2, 2, 1, false>
        <<<dim3(2048), dim3(256), 0, stream>>>(
        x, (const float4*)wp1, c1_b, c1_kn, c1_sw, c1_w1, c1_w2, bn1_g, bn1_b,
        zbuf, h1, 2, 32, 64, 64, 64, 128, 16, 4);
    // L2: (2,32,32^3)->(2,64,16^3). r17 config (measured 121.3us): CSPLIT=2 x
    // 2 spatial waves, dbuf, scalar weights. grid 1024.
    spline_block_kernel<256, 32, 2, 4, 2, 4, 8, 1, 1, 2, false>
        <<<dim3(1024), dim3(256), 0, stream>>>(
        h1, (const float4*)wp2, c2_b, c2_kn, c2_sw, c2_w1, c2_w2, bn2_g, bn2_b,
        zbuf, h2, 2, 64, 32, 32, 32, 32, 4, 1);
    // L3: (2,64,16^3)->pooled[2,128] directly (FMEAN): CSPLIT=4, grid 512.
    // No h3 materialization; mean_kernel dispatch eliminated.
    spline_block_kernel<256, 64, 4, 4, 2, 4, 8, 1, 1, 1, true>
        <<<dim3(512), dim3(256), 0, stream>>>(
        h2, (const float4*)wp3, c3_b, c3_kn, c3_sw, c3_w1, c3_w2, bn3_g, bn3_b,
        zbuf, pooled, 2, 128, 16, 16, 16, 8, 2, 1);
    // fc head (pooled -> d_out)
    fc_kernel<<<dim3(1), dim3(256), 0, stream>>>(pooled, fc1_w, fc1_b, fc2_w, fc2_b,
                                                 (float*)d_out);
}

// Round 10
// 318.466 us; speedup vs baseline: 1.2195x; 1.0067x over previous
//
#include <hip/hip_runtime.h>
#include <math.h>

// ConvKAN3D: 3x [conv3d(3x3x3,pad1) -> cubic KAN spline + SiLU -> BN(eval) -> maxpool 2x2x2]
// then global mean pool + fc1/relu/fc2.
// r20: L2 G=8 (uniform residency) + fc FUSED INTO L3 (last-block pattern).
//  - L2: G 4->8, grid 1024->512. Halves DS reads + staging per FMA (64 ds_read
//    per 1728 FMA) and makes all 512 blocks co-resident at 2/CU (capacity 3) ->
//    single uniform round (r19 measured: grid 1024 @ 3/CU = ragged 768+256,
//    avg 25% occupancy, 120.5us). G=8 is safe now that weights are SGPR
//    (r8's G=8 spill was with 28 per-lane weight VGPRs); watch WRITE_SIZE.
//  - L3: after pooled atomicAdds, __syncthreads (drains each wave's atomics) ->
//    tid0 __threadfence + counter atomicAdd; last block coherently re-reads
//    pooled via atomicAdd(p,0.0f), runs fc1/fc2 in-kernel (tile LDS reused).
//    fc dispatch + gap eliminated. cnt zeroed in repack tail (replay-safe).
//  - Kept from r19 (measured best): K-loop dbuf DMA + vmcnt(6), scalar s_load
//    weights, L1 r12 config, fused mean, repack with zero-tail. 4 dispatches.
// Measured-dead-ends (do not retry): reg-staged prefetch w/ r[64] (r18 spill),
// LDS padding/alignment (r15: conflict counter structural), TPB=128 (r13),
// 1 block/CU (r16-L1), single-block fused head as separate kernel (r17),
// cin-split via global atomics on conv accumulators (r5). launch_bounds (TPB,2).
// CSPLIT scratch indexed by (cg,sw_) jointly (r14 replay race).

#define GLOBAL_AS __attribute__((address_space(1)))
#define LDS_AS    __attribute__((address_space(3)))

static __device__ __forceinline__ void async_ld16(const float* g, float* l) {
    __builtin_amdgcn_global_load_lds((const GLOBAL_AS void*)g, (LDS_AS void*)l,
                                     16, 0, 0);
}

// Pack [C][CIN][27] conv weights -> [C*CIN][28] (16B-aligned float4 x 7, tail 0).
// Tail threads zero zbuf, pooled, and the fc completion counter (replay-safe).
__global__ __launch_bounds__(256) void repack_kernel(
    const float* __restrict__ w1, const float* __restrict__ w2,
    const float* __restrict__ w3,
    float* __restrict__ o1, float* __restrict__ o2, float* __restrict__ o3,
    float* __restrict__ zbuf, float* __restrict__ pooled,
    float* __restrict__ cntf)
{
    const int i = blockIdx.x * 256 + threadIdx.x;   // (c,ci) pair id
    const float* src;
    float* dst;
    if (i < 32)            { src = w1 + i * 27;           dst = o1 + i * 28; }
    else if (i < 2080)     { const int j = i - 32;   src = w2 + j * 27; dst = o2 + j * 28; }
    else if (i < 10272)    { const int j = i - 2080; src = w3 + j * 27; dst = o3 + j * 28; }
    else {
        if (i < 10288) zbuf[i - 10272] = 0.0f;
        else if (i < 10544) pooled[i - 10288] = 0.0f;
        else if (i < 10560) cntf[i - 10544] = 0.0f;
        return;
    }
#pragma unroll
    for (int t = 0; t < 27; t++) dst[t] = src[t];
    dst[27] = 0.0f;
}

template <int TPB_, int CIN, int CSPLIT, int G,
          int WDT, int WHT, int WWT, int BD, int BH, int BW, bool FMEAN>
__global__ __launch_bounds__(TPB_, 2) void spline_block_kernel(
    const float* __restrict__ x,    // [N, CIN, D, H, W]
    const float4* __restrict__ wpk, // [Cout*CIN][7] packed conv weights
    const float* __restrict__ cb,   // [Cout]
    const float* __restrict__ knots,// [10]
    const float* __restrict__ sw,   // [Cout, 10]
    const float* __restrict__ w1,
    const float* __restrict__ w2,
    const float* __restrict__ g,
    const float* __restrict__ beta,
    const float* __restrict__ zbuf, // >=64B of zeros (16B aligned)
    float* __restrict__ out,        // FMEAN? pooled[N*Cout] : [N,Cout,D/2,H/2,W/2]
    const float* __restrict__ fw1, const float* __restrict__ fb1,
    const float* __restrict__ fw2, const float* __restrict__ fb2,
    float* __restrict__ dout, int* __restrict__ cnt,
    int N, int Cout, int D, int H, int W,
    int ntiles, int nthw, int ntw)
{
    constexpr int NSW    = BD * BH * BW;       // spatial wave-tiles per block
    constexpr int NW     = TPB_ / 64;          // waves per block
    constexpr int CPG    = CIN / CSPLIT;       // cins per cin-group
    constexpr int ID     = 2 * WDT + 2;        // input planes (d) per wave tile
    constexpr int IH     = 2 * WHT + 2;        // input rows (h) per wave tile
    constexpr int CHK    = (WWT + 4) / 2;      // 16B chunks per input row
    constexpr int PITCH  = CHK * 4;            // dwords per row
    constexpr int ROWS   = ID * IH;
    constexpr int CHUNKS = ROWS * CHK;
    constexpr int PHYS   = CHUNKS * 4;         // dwords per wave buffer
    constexpr int NCH    = (CHUNKS + 63) / 64; // DMA issues per cin per lane
    constexpr int BUFS   = (CPG > 1) ? 2 : 1;
    static_assert(NW == NSW * CSPLIT, "waves = spatial-tiles x cin-split");
    static_assert(WDT * WHT * WWT == 64, "one wave per spatial tile");
    static_assert(CIN % CSPLIT == 0, "cin divisible");
    static_assert(G == 4 || G == 8, "acc layout assumes G in {4,8}");
    static_assert(NCH <= 32, "mask fits u32");
    static_assert(NCH == 6, "s_waitcnt vmcnt(6) literal assumes 6 issues/cin");
    static_assert(CSPLIT == 1 ||
                  (CSPLIT - 1) * NSW * 64 * G * 8 <= NW * BUFS * PHYS,
                  "reduction scratch fits in tile");
    static_assert(!FMEAN || TPB_ == 256, "fused fc assumes 256 threads");

    __shared__ __align__(16) float tile[NW][BUFS][PHYS];
    __shared__ float4 stbl[G * 11];            // spline prefix coeffs {A,3B,3C,D}
    __shared__ int lastblk;

    const int PD = D >> 1, PH = H >> 1, PW = W >> 1;
    const int groups = Cout / G;
    const int tid  = threadIdx.x;
    const int wv   = tid >> 6;                 // wave id
    const int lane = tid & 63;
    const int sw_  = wv % NSW;                 // spatial wave-tile id
    const int cg   = wv / NSW;                 // cin-group id

    const int bx      = blockIdx.x;
    const int tile_id = bx % ntiles;
    const int t1      = bx / ntiles;
    const int grp     = t1 % groups;
    const int n       = t1 / groups;
    const int c0      = grp * G;
    const int cinbase = cg * CPG;
    // wave-uniform cin base -> uniform weight addresses -> SMEM s_load (lgkmcnt,
    // separate counter from the staging DMAs' vmcnt, zero VGPR cost)
    const int cinbase_u = __builtin_amdgcn_readfirstlane(cinbase);

    const int td  = tile_id / nthw;
    const int rem = tile_id % nthw;
    const int th_ = rem / ntw;
    const int tw_ = rem % ntw;

    // spline prefix-coeff table (covered by the single initial barrier)
    for (int i = tid; i < G * 11; i += TPB_) {
        const int gg  = i / 11;
        const int cnt2 = i % 11;
        const int c   = c0 + gg;
        float A = 0.f, B3 = 0.f, C3 = 0.f, Dd = 0.f;
        for (int j = 0; j < cnt2; j++) {
            const float s = sw[c * 10 + j];
            const float k = knots[j];
            A  += s;
            B3 += 3.0f * s * k;
            C3 += 3.0f * s * k * k;
            Dd += s * k * k * k;
        }
        stbl[i] = make_float4(A, B3, C3, Dd);
    }

    // wave spatial origin (pooled coords)
    const int swd = sw_ / (BH * BW);
    const int r2  = sw_ % (BH * BW);
    const int swh = r2 / BW;
    const int sww = r2 % BW;
    const int pd0 = td  * (BD * WDT) + swd * WDT;
    const int ph0 = th_ * (BH * WHT) + swh * WHT;
    const int pw0 = tw_ * (BW * WWT) + sww * WWT;

    const int pwl = lane % WWT;
    const int phl = (lane / WWT) % WHT;
    const int pdl = lane / (WWT * WHT);

    const int d0 = 2 * pd0 - 1, h0 = 2 * ph0 - 1;
    const int w0 = 2 * pw0 - 1;
    const int wb = w0 & ~3;                    // 4-dword aligned chunk origin
    const int woff = w0 - wb;                  // always 3

    // per-chunk global offsets + validity (per wave tile, same for all cins)
    int off[NCH];
    unsigned vm = 0;
#pragma unroll
    for (int k = 0; k < NCH; k++) {
        const int chunk = lane + 64 * k;
        const int row = chunk / CHK, cs = chunk - row * CHK;
        const int dz = row / IH, hy = row - dz * IH;
        const int dd = d0 + dz, hh = h0 + hy;
        const int wsd = wb + cs * 4;
        const bool ok = (chunk < CHUNKS) &
                        ((unsigned)dd < (unsigned)D) &
                        ((unsigned)hh < (unsigned)H) &
                        ((unsigned)wsd < (unsigned)W);
        off[k] = ok ? (dd * H + hh) * W + wsd : 0;
        vm |= (unsigned)ok << k;
    }

    const size_t chstride = (size_t)D * H * W;
    const float* xn = x + (size_t)n * CIN * chstride;

    float acc[G][8];
#pragma unroll
    for (int gg = 0; gg < G; gg++)
#pragma unroll
        for (int i = 0; i < 8; i++) acc[gg][i] = 0.0f;

    __syncthreads();   // stbl visible; vmcnt drained (clean slate)

    auto stage = [&](int ci, int buf) {
        const float* xc = xn + (size_t)ci * chstride;
        float* dst = &tile[wv][buf][0];
#pragma unroll
        for (int k = 0; k < NCH; k++) {
            const int chunk = lane + 64 * k;
            if ((k + 1) * 64 <= CHUNKS || chunk < CHUNKS) {
                const float* src = ((vm >> k) & 1) ? (xc + off[k]) : zbuf;
                async_ld16(src, dst + chunk * 4);
            }
        }
    };

    // prologue: each wave stages its first cin into its buf 0
    stage(cinbase, 0);

#pragma unroll 1
    for (int s = 0; s < CPG; s++) {
        const int cur = s & (BUFS - 1);
        if (s + 1 < CPG) {
            stage(cinbase + s + 1, cur ^ 1);   // 6 DMA issues, stay in flight
            asm volatile("s_waitcnt vmcnt(6)" ::: "memory");  // cin s landed
        } else {
            asm volatile("s_waitcnt vmcnt(0)" ::: "memory");
        }

        const int ci_u = cinbase_u + s;        // wave-uniform weight row
        const float* tb = &tile[wv][cur][0];
        float r[64];
#pragma unroll
        for (int dz = 0; dz < 4; dz++)
#pragma unroll
        for (int dy = 0; dy < 4; dy++) {
            const int rb = ((2 * pdl + dz) * IH + (2 * phl + dy)) * PITCH +
                           woff + 2 * pwl;
            r[(dz * 4 + dy) * 4 + 0] = tb[rb + 0];
            r[(dz * 4 + dy) * 4 + 1] = tb[rb + 1];
            r[(dz * 4 + dy) * 4 + 2] = tb[rb + 2];
            r[(dz * 4 + dy) * 4 + 3] = tb[rb + 3];
        }

#pragma unroll
        for (int gg = 0; gg < G; gg++) {
            // uniform address -> s_load (SMEM), separate lgkm counter
            const float4* wq = wpk + ((size_t)(c0 + gg) * CIN + ci_u) * 7;
            float4 q[7];
#pragma unroll
            for (int ch = 0; ch < 7; ch++) q[ch] = wq[ch];
#pragma unroll
            for (int ch = 0; ch < 7; ch++) {
#pragma unroll
                for (int j = 0; j < 4; j++) {
                    const int tap = ch * 4 + j;
                    if (tap < 27) {
                        const float wvj = (j == 0) ? q[ch].x : (j == 1) ? q[ch].y
                                        : (j == 2) ? q[ch].z : q[ch].w;
                        const int kd = tap / 9, kh = (tap % 9) / 3, kw = tap % 3;
#pragma unroll
                        for (int od = 0; od < 2; od++)
#pragma unroll
                        for (int oh = 0; oh < 2; oh++)
#pragma unroll
                        for (int ow = 0; ow < 2; ow++)
                            acc[gg][(od * 2 + oh) * 2 + ow] =
                                fmaf(wvj,
                                     r[((od + kd) * 4 + (oh + kh)) * 4 + (ow + kw)],
                                     acc[gg][(od * 2 + oh) * 2 + ow]);
                    }
                }
            }
        }
    }

    // combine partial accumulators across cin-groups (scratch aliases tile).
    // scratch MUST be indexed by (cg, sw_) jointly (r14 replay race).
    float* af = &acc[0][0];
    if (CSPLIT > 1) {
        __syncthreads();                        // all waves done with their tiles
        float* scratch = &tile[0][0][0];
        if (cg > 0) {
#pragma unroll
            for (int idx = 0; idx < G * 8; idx++)
                scratch[((idx * (CSPLIT - 1) + (cg - 1)) * NSW + sw_) * 64 + lane]
                    = af[idx];
        }
        __syncthreads();
        if (cg == 0) {
#pragma unroll
            for (int idx = 0; idx < G * 8; idx++) {
                float s2 = af[idx];
                for (int j = 0; j < CSPLIT - 1; j++)
                    s2 += scratch[((idx * (CSPLIT - 1) + j) * NSW + sw_) * 64 + lane];
                af[idx] = s2;
            }
        }
    }

    // epilogue (cin-group 0): bias + spline (prefix-Horner) + SiLU + BN + maxpool
    if (cg == 0) {
        const int pdg = pd0 + pdl, phg = ph0 + phl, pwg = pw0 + pwl;
        const float inv_vol = 1.0f / (float)(PD * PH * PW);
#pragma unroll
        for (int gg = 0; gg < G; gg++) {
            const int c = c0 + gg;
            const float bias = cb[c];
            const float W1 = w1[c], W2 = w2[c];
            const float scale = g[c] * rsqrtf(1.0f + 1e-5f);
            const float bb = beta[c];
            float m = -INFINITY;
#pragma unroll
            for (int i = 0; i < 8; i++) {
                const float y = acc[gg][i] + bias;
                int idx = (int)floorf((y + 1.0f) * 4.5f) + 1;
                idx = min(max(idx, 0), 10);
                const float4 cf = stbl[gg * 11 + idx];
                const float sp = ((cf.x * y - cf.y) * y + cf.z) * y - cf.w;
                const float silu = y / (1.0f + __expf(-y));
                const float o = fmaf(W1 * sp + W2 * silu, scale, bb);
                m = fmaxf(m, o);
            }
            if constexpr (FMEAN) {
                float ssum = m;
#pragma unroll
                for (int o2 = 32; o2 > 0; o2 >>= 1)
                    ssum += __shfl_down(ssum, o2, 64);
                if (lane == 0)
                    atomicAdd(&out[(size_t)n * Cout + c], ssum * inv_vol);
            } else {
                out[((size_t)(n * Cout + c) * PD + pdg) * PH * PW +
                    phg * PW + pwg] = m;
            }
        }
    }

    // fused fc head: LAST block (device-scope counter) computes fc1/fc2.
    if constexpr (FMEAN) {
        __syncthreads();   // per-wave vmcnt(0) drain -> all atomics retired
        if (tid == 0) {
            __threadfence();                         // publish this block's adds
            lastblk = (atomicAdd(cnt, 1) == (int)gridDim.x - 1);
        }
        __syncthreads();
        if (lastblk) {
            __threadfence();                         // order before coherent reads
            float* fl = &tile[0][0][0];              // plds[256] | hb[2][256]
            fl[tid] = atomicAdd(&out[tid], 0.0f);    // coherent read of pooled
            __syncthreads();
#pragma unroll
            for (int nn = 0; nn < 2; nn++) {
                float s = fb1[tid];
                for (int k = 0; k < 128; k++)
                    s = fmaf(fl[nn * 128 + k], fw1[tid * 128 + k], s);
                fl[256 + nn * 256 + tid] = fmaxf(s, 0.0f);
            }
            __syncthreads();
            const int wid = tid >> 6, l2 = tid & 63;
            const int nn = wid >> 1, oo = wid & 1;
            float s = 0.0f;
            for (int k = l2; k < 256; k += 64)
                s += fl[256 + nn * 256 + k] * fw2[oo * 256 + k];
#pragma unroll
            for (int o2 = 32; o2 > 0; o2 >>= 1) s += __shfl_down(s, o2, 64);
            if (l2 == 0) dout[nn * 2 + oo] = s + fb2[oo];
        }
    }
}

extern "C" void kernel_launch(void* const* d_in, const int* in_sizes, int n_in,
                              void* d_out, int out_size, void* d_ws, size_t ws_size,
                              hipStream_t stream) {
    const float* x      = (const float*)d_in[0];
    const float* c1_w   = (const float*)d_in[1];
    const float* c1_b   = (const float*)d_in[2];
    const float* c1_kn  = (const float*)d_in[3];
    const float* c1_sw  = (const float*)d_in[4];
    const float* c1_w1  = (const float*)d_in[5];
    const float* c1_w2  = (const float*)d_in[6];
    const float* bn1_g  = (const float*)d_in[7];
    const float* bn1_b  = (const float*)d_in[8];
    const float* c2_w   = (const float*)d_in[9];
    const float* c2_b   = (const float*)d_in[10];
    const float* c2_kn  = (const float*)d_in[11];
    const float* c2_sw  = (const float*)d_in[12];
    const float* c2_w1  = (const float*)d_in[13];
    const float* c2_w2  = (const float*)d_in[14];
    const float* bn2_g  = (const float*)d_in[15];
    const float* bn2_b  = (const float*)d_in[16];
    const float* c3_w   = (const float*)d_in[17];
    const float* c3_b   = (const float*)d_in[18];
    const float* c3_kn  = (const float*)d_in[19];
    const float* c3_sw  = (const float*)d_in[20];
    const float* c3_w1  = (const float*)d_in[21];
    const float* c3_w2  = (const float*)d_in[22];
    const float* bn3_g  = (const float*)d_in[23];
    const float* bn3_b  = (const float*)d_in[24];
    const float* fc1_w  = (const float*)d_in[25];
    const float* fc1_b  = (const float*)d_in[26];
    const float* fc2_w  = (const float*)d_in[27];
    const float* fc2_b  = (const float*)d_in[28];

    float* ws = (float*)d_ws;
    float* h1     = ws;                  // 2*32*32^3 = 2,097,152 fl
    float* h2     = h1 + 2097152;        // 2*64*16^3 =   524,288 fl
    float* pooled = h2 + 524288;         // 256 fl (atomic accumulator)
    float* zbuf   = pooled + 256;        // 64 B zeros (16B aligned)
    float* cntf   = zbuf + 16;           // 16 fl (fc completion counter at [0])
    float* wp1    = cntf + 16;           // 32*1*28   =       896 fl (16B aligned)
    float* wp2    = wp1 + 896;           // 64*32*28  =    57,344 fl
    float* wp3    = wp2 + 57344;         // 128*64*28 =   229,376 fl

    // pack conv weights (pitch-28 float4x7) + zero zbuf/pooled/cnt (replay-safe)
    repack_kernel<<<dim3(42), dim3(256), 0, stream>>>(
        c1_w, c2_w, c3_w, wp1, wp2, wp3, zbuf, pooled, cntf);

    // All layers: wave tile 2x4x8 (ID=6, IH=10, PITCH=24, 6 DMA issues/cin).
    // L1: (2,1,64^3)->(2,32,32^3). r12 config (measured 33.6us): 4 spatial
    // waves (2x2x1), grid 2048.
    spline_block_kernel<256, 1, 1, 4, 2, 4, 8, 2, 2, 1, false>
        <<<dim3(2048), dim3(256), 0, stream>>>(
        x, (const float4*)wp1, c1_b, c1_kn, c1_sw, c1_w1, c1_w2, bn1_g, bn1_b,
        zbuf, h1, nullptr, nullptr, nullptr, nullptr, nullptr, nullptr,
        2, 32, 64, 64, 64, 128, 16, 4);
    // L2: (2,32,32^3)->(2,64,16^3). G=8: CSPLIT=2 x 2 spatial waves, grid 512
    // -> ALL blocks co-resident (2/CU, capacity 3) = one uniform round; DS reads
    // per FMA halved vs G=4.
    spline_block_kernel<256, 32, 2, 8, 2, 4, 8, 1, 1, 2, false>
        <<<dim3(512), dim3(256), 0, stream>>>(
        h1, (const float4*)wp2, c2_b, c2_kn, c2_sw, c2_w1, c2_w2, bn2_g, bn2_b,
        zbuf, h2, nullptr, nullptr, nullptr, nullptr, nullptr, nullptr,
        2, 64, 32, 32, 32, 32, 4, 1);
    // L3: (2,64,16^3)->pooled[2,128] (FMEAN) + last-block fused fc -> d_out.
    // CSPLIT=4, grid 512.
    spline_block_kernel<256, 64, 4, 4, 2, 4, 8, 1, 1, 1, true>
        <<<dim3(512), dim3(256), 0, stream>>>(
        h2, (const float4*)wp3, c3_b, c3_kn, c3_sw, c3_w1, c3_w2, bn3_g, bn3_b,
        zbuf, pooled, fc1_w, fc1_b, fc2_w, fc2_b, (float*)d_out, (int*)cntf,
        2, 128, 16, 16, 16, 8, 2, 1);
}